// Round 1
// baseline (206.239 us; speedup 1.0000x reference)
//
#include <hip/hip_runtime.h>

namespace {
constexpr int CC   = 10;                  // cluster gap window C
constexpr int TT   = 500;                 // time steps
constexpr int NN   = 128;                 // neurons per batch row == blockDim
constexpr int KMAX = TT / (CC + 1) + 1;   // 46: max possible clusters
}

__global__ void zero_loss_kernel(float* out) {
    if (threadIdx.x == 0) out[0] = 0.0f;
}

__global__ __launch_bounds__(NN, 1)
void atca_tca_loss_kernel(const float* __restrict__ vmem,
                          const int*   __restrict__ labels,
                          float*       __restrict__ out) {
    const int b = blockIdx.x;
    const int n = threadIdx.x;
    const float* __restrict__ src = vmem + (size_t)b * TT * NN + n;
    const int label = labels[b * NN + n];

    __shared__ float clmax[KMAX][NN];   // per-thread column of cluster span-maxes
    __shared__ float redbuf[NN / 64];

    // streaming state
    float ring[CC];                 // last C values of v (delay buffer), static-indexed
    int   ls   = -(1 << 20);        // last spike time
    int   nc   = 0;                 // cluster count
    float ccm  = -1e30f;            // current cluster span max
    float rmax = -1e30f;            // max of v since last spike (exclusive of spike)
    float vmax = -1e30f;            // global max
    int   tm   = 0;                 // first argmax
    float m0   = -1e30f;            // max over unmasked positions
    bool  hasu = false;             // any unmasked position exists (== !full0)

    auto loadChunk = [&](float (&vv)[CC], int tc) {
        #pragma unroll
        for (int j = 0; j < CC; ++j)
            vv[j] = src[(size_t)(tc + j) * NN];
    };

    auto procChunk = [&](const float (&vv)[CC], int tc) {
        #pragma unroll
        for (int j = 0; j < CC; ++j) {
            const int t = tc + j;
            const float v = vv[j];
            rmax = fmaxf(rmax, v);
            if (v >= 0.0f) {                       // spike
                if (t - ls > CC) {                 // starts a new cluster
                    if (nc > 0) clmax[nc - 1][n] = ccm;  // finalize previous
                    ccm = v;
                    ++nc;
                } else {                           // continues cluster: fold gap+self max
                    ccm = fmaxf(ccm, rmax);
                }
                ls = t;
                rmax = -1e30f;
            }
            if (v > vmax) { vmax = v; tm = t; }    // strict > keeps first argmax
            if (tc >= CC) {
                // evaluate u = t - C: unmasked(u) <=> last_spike_at(u+C) < u-C
                const float vu = ring[j];          // v[t - C]
                if (ls < t - 2 * CC) { m0 = fmaxf(m0, vu); hasu = true; }
            }
            ring[j] = v;
        }
    };

    // main pass, double-buffered chunks of C (500 = 25 * 20)
    float va[CC], vb[CC];
    loadChunk(va, 0);
    for (int tc = 0; tc < TT; tc += 2 * CC) {
        loadChunk(vb, tc + CC);
        procChunk(va, tc);
        if (tc + 2 * CC < TT) loadChunk(va, tc + 2 * CC);
        procChunk(vb, tc + CC);
    }
    // epilogue: evaluate trailing u = T-C .. T-1 (window clipped at T)
    #pragma unroll
    for (int j = 0; j < CC; ++j) {
        const int u = (TT - CC) + j;
        const float vu = ring[j];
        if (ls < u - CC) { m0 = fmaxf(m0, vu); hasu = true; }
    }
    if (nc > 0) clmax[nc - 1][n] = ccm;            // finalize last cluster

    // -------- optional pass 2: m_rest (rare; wave-uniform gate) --------
    const bool need2 = (label > nc) && hasu && (label - nc >= 2);
    float m2 = -1e30f;
    bool  has2 = false;
    if (__any((int)need2)) {
        int ls2 = -(1 << 20);
        float ring2[CC];
        const int wlo = tm - CC / 2, whi = tm + CC / 2;
        for (int tc = 0; tc < TT; tc += CC) {
            float vv[CC];
            #pragma unroll
            for (int j = 0; j < CC; ++j) vv[j] = src[(size_t)(tc + j) * NN];
            #pragma unroll
            for (int j = 0; j < CC; ++j) {
                const int t = tc + j;
                const float v = vv[j];
                if (v >= 0.0f) ls2 = t;
                if (tc >= CC) {
                    const int u = t - CC;
                    const float vu = ring2[j];
                    if (ls2 < u - CC && (u < wlo || u > whi)) {
                        m2 = fmaxf(m2, vu); has2 = true;
                    }
                }
                ring2[j] = v;
            }
        }
        #pragma unroll
        for (int j = 0; j < CC; ++j) {
            const int u = (TT - CC) + j;
            const float vu = ring2[j];
            if (ls2 < u - CC && (u < wlo || u > whi)) {
                m2 = fmaxf(m2, vu); has2 = true;
            }
        }
    }

    // -------- branch select --------
    float contrib = 0.0f;
    if (label > nc) {
        if (!hasu) {
            contrib = vmax;                         // full0 -> vmax
        } else {
            const float dE = (float)(label - nc);   // >= 1
            const float mrest = has2 ? m2 : vmax;   // full2 -> vmax surrogate
            contrib = -((m0 + (dE - 1.0f) * mrest) / dE);
        }
    } else if (label < nc) {
        const int k = nc - label;                   // 1..nc
        float s = 0.0f;
        for (int i = 0; i < k; ++i) {               // sum k smallest cluster maxes
            float mn = 1e30f; int mj = 0;
            for (int jj = 0; jj < nc; ++jj) {
                const float x = clmax[jj][n];
                if (x < mn) { mn = x; mj = jj; }
            }
            s += mn;
            clmax[mj][n] = 1e30f;                   // mark used
        }
        contrib = s / (float)k;
    }

    // spike_output
    out[1 + b * NN + n] = (float)nc;

    // loss reduction: wave shuffle -> LDS -> one atomic per block
    float wsum = contrib;
    #pragma unroll
    for (int off = 32; off > 0; off >>= 1)
        wsum += __shfl_down(wsum, off, 64);
    if ((n & 63) == 0) redbuf[n >> 6] = wsum;
    __syncthreads();
    if (n == 0) atomicAdd(out, redbuf[0] + redbuf[1]);
}

extern "C" void kernel_launch(void* const* d_in, const int* in_sizes, int n_in,
                              void* d_out, int out_size, void* d_ws, size_t ws_size,
                              hipStream_t stream) {
    const float* vmem   = (const float*)d_in[0];
    // d_in[1] (vlastmem) and d_in[3] (ratio) are unused by the reference forward.
    const int*   labels = (const int*)d_in[2];
    float*       out    = (float*)d_out;

    const int B = in_sizes[2] / NN;   // 256

    hipLaunchKernelGGL(zero_loss_kernel, dim3(1), dim3(64), 0, stream, out);
    hipLaunchKernelGGL(atca_tca_loss_kernel, dim3(B), dim3(NN), 0, stream,
                       vmem, labels, out);
}